// Round 7
// baseline (172.889 us; speedup 1.0000x reference)
//
#include <hip/hip_runtime.h>
#include <hip/hip_bf16.h>
#include <math.h>

// Problem constants
#define BATCH 2
#define SEQ   2048
#define DIM   1024
#define HEADS 16
#define DH    64
#define MROWS (BATCH*SEQ)      // 4096
#define NTOT  3072             // gemm output cols: q(1024) | k(1024) | v(1024)
#define QKW   2048             // qk buffer width (v goes straight to vT)
#define KDIM  1024

typedef float f32x4 __attribute__((ext_vector_type(4)));
typedef __bf16 bf16x8 __attribute__((ext_vector_type(8)));
typedef __bf16 bf16x4 __attribute__((ext_vector_type(4)));

__device__ __forceinline__ void gload_lds16(const void* g, void* l) {
    // async global->LDS, 16B per lane; LDS dest must be wave-uniform base (+lane*16 implicit)
    __builtin_amdgcn_global_load_lds((__attribute__((address_space(1))) void*)g,
                                     (__attribute__((address_space(3))) void*)l,
                                     16, 0, 0);
}

// ---------------------------------------------- prep: cast x -> bf16  +  transpose W -> Wt
// blocks [0,4096): cast 1 float4/thread.  blocks [4096,4864): 64x64 transpose tiles.
__global__ void prep_kernel(const float* __restrict__ x,
                            const float* __restrict__ Wqk, const float* __restrict__ Wv,
                            __bf16* __restrict__ xb, __bf16* __restrict__ Wt) {
    __shared__ float T[64*65];
    const int bx = blockIdx.x;
    const int tid = threadIdx.x;
    if (bx < 4096) {
        int i = bx * 256 + tid;                   // 1M float4 = 4M floats exactly
        float4 f = ((const float4*)x)[i];
        bf16x4 o;
        o.x = (__bf16)f.x; o.y = (__bf16)f.y; o.z = (__bf16)f.z; o.w = (__bf16)f.w;
        ((bf16x4*)xb)[i] = o;
    } else {
        const int t = bx - 4096;                  // 0..767
        const int n0 = (t % 48) * 64;
        const int k0 = (t / 48) * 64;
#pragma unroll
        for (int i = 0; i < 16; ++i) {
            int idx = i*256 + tid;
            int kk = idx >> 6, nn = idx & 63;
            int n = n0 + nn;
            float v = (n < 2048) ? Wqk[(size_t)(k0+kk)*2048 + n]
                                 : Wv [(size_t)(k0+kk)*1024 + (n - 2048)];
            T[kk*65 + nn] = v;
        }
        __syncthreads();
#pragma unroll
        for (int i = 0; i < 16; ++i) {
            int idx = i*256 + tid;
            int nn = idx >> 6, kk = idx & 63;
            Wt[(size_t)(n0+nn)*KDIM + k0 + kk] = (__bf16)T[kk*65 + nn];
        }
    }
}

// ---------------------------------------------------------------- GEMM v2: BK=64, swizzled LDS
// [qk | v] = x * Wt^T + bias ; qk cols<2048 -> qk buffer row-major (stride QKW),
// v cols>=2048 -> written TRANSPOSED to vT[bh][dv][s].
#define BM 128
#define BN 128
#define BK 64

__global__ __launch_bounds__(256) void gemm_qkv_kernel(const __bf16* __restrict__ A,
                                                       const __bf16* __restrict__ Bt,
                                                       const float* __restrict__ bqk,
                                                       const float* __restrict__ bv,
                                                       __bf16* __restrict__ qk,
                                                       __bf16* __restrict__ vT) {
    __shared__ alignas(16) __bf16 As[BM*BK];      // [row][chunk-swizzled 8x16B]
    __shared__ alignas(16) __bf16 Bs[BN*BK];
    const int tid = threadIdx.x;
    const int wv = tid >> 6, ln = tid & 63;
    const int quad = ln >> 4, lm = ln & 15;
    const int m0 = blockIdx.y * BM, n0 = blockIdx.x * BN;
    const int wm = (wv >> 1) * 64, wn = (wv & 1) * 64;
    const int sw = lm & 7;                         // frag-read swizzle key (row&7 == lm&7)

    f32x4 acc[4][4] = {};

    for (int kt = 0; kt < KDIM/BK; ++kt) {
        const int k0 = kt * BK;
        __syncthreads();          // prev iteration's ds_reads complete before overwrite
#pragma unroll
        for (int i = 0; i < 4; ++i) {
            int slot = wv*256 + i*64 + ln;        // LDS chunk slot 0..1023 (16B chunks)
            int row = slot >> 3, p = slot & 7;
            int cc = (p ^ (row & 7)) * 8;         // fetch the chunk that belongs at slot p
            gload_lds16(A  + (size_t)(m0 + row)*KDIM + k0 + cc, &As[(wv*256 + i*64)*8]);
            gload_lds16(Bt + (size_t)(n0 + row)*KDIM + k0 + cc, &Bs[(wv*256 + i*64)*8]);
        }
        __syncthreads();          // drains vmcnt(0): LDS tiles ready
#pragma unroll
        for (int kf = 0; kf < 2; ++kf) {          // two 32-wide K halves per staged tile
            bf16x8 af[4], bfr[4];
#pragma unroll
            for (int mt = 0; mt < 4; ++mt)
                af[mt] = *(const bf16x8*)&As[(wm + mt*16 + lm)*BK + (((kf<<2)|quad) ^ sw)*8];
#pragma unroll
            for (int nt = 0; nt < 4; ++nt)
                bfr[nt] = *(const bf16x8*)&Bs[(wn + nt*16 + lm)*BK + (((kf<<2)|quad) ^ sw)*8];
#pragma unroll
            for (int mt = 0; mt < 4; ++mt)
#pragma unroll
                for (int nt = 0; nt < 4; ++nt)
                    acc[mt][nt] = __builtin_amdgcn_mfma_f32_16x16x32_bf16(af[mt], bfr[nt], acc[mt][nt], 0, 0, 0);
        }
    }
    // epilogue. C/D layout: row = quad*4+r, col = lm (m89-verified). Branch is block-uniform.
    if (n0 < 2048) {
#pragma unroll
        for (int mt = 0; mt < 4; ++mt) {
            int rbase = m0 + wm + mt*16 + quad*4;
#pragma unroll
            for (int nt = 0; nt < 4; ++nt) {
                int col = n0 + wn + nt*16 + lm;
                float bs = bqk[col];
#pragma unroll
                for (int r = 0; r < 4; ++r)
                    qk[(size_t)(rbase + r)*QKW + col] = (__bf16)(acc[mt][nt][r] + bs);
            }
        }
    } else {
        // v path: vT[((b*16+h)*64 + dv)*SEQ + s]; r-values are s-contiguous -> 8B stores
#pragma unroll
        for (int mt = 0; mt < 4; ++mt) {
            int rbase = m0 + wm + mt*16 + quad*4;       // global token index, mult of 4
            int bb = rbase >> 11, s = rbase & 2047;     // rbase..rbase+3 same batch
#pragma unroll
            for (int nt = 0; nt < 4; ++nt) {
                int cv = n0 + wn + nt*16 + lm - 2048;   // v column 0..1023
                int hh = cv >> 6, dv = cv & 63;
                float bs = bv[cv];
                bf16x4 pk;
#pragma unroll
                for (int r = 0; r < 4; ++r) pk[r] = (__bf16)(acc[mt][nt][r] + bs);
                *(bf16x4*)&vT[(((size_t)(bb*16 + hh))*64 + dv)*SEQ + s] = pk;
            }
        }
    }
}

// ---------------------------------------------------------------- flash attention v6
// BQ=128: 32 q-rows/wave (2 m-tiles) -> kfrag/vfrag amortized over 2x MFMA:
//   20 b128 reads per 32 MFMA (was 18 per 16). Transposed-S + swizzle + no-max + dbuf kept.
// grid (32 bh, 16 qt pair-balanced), 256 thr = 4 waves; KV tile 64.
// LDS 48 KB -> 3 blocks/CU (__launch_bounds__(256,3)); grid supplies 2/CU.

__global__ __launch_bounds__(256, 3) void attn_kernel(const __bf16* __restrict__ qk,
                                                      const __bf16* __restrict__ vT,
                                                      float* __restrict__ out) {
    const int bh = blockIdx.x;
    const int b = bh >> 4, h = bh & 15;
    const int yy = (int)blockIdx.y;
    const int qt = (yy < 8) ? (15 - yy) : (yy - 8); // paired: CU gets qt + (15-qt) = const work
    const int qb = qt * 128;
    const int tid = threadIdx.x, wv = tid >> 6, ln = tid & 63;
    const int quad = ln >> 4, lm = ln & 15;
    const int q0w = qb + wv*32;                     // this wave's 32 q-rows

    __shared__ alignas(16) __bf16 Ks[2][64*64];     // [buf][kv][feat], chunk-swizzled
    __shared__ alignas(16) __bf16 Vs[2][64*64];     // [buf][dv][kv],  chunk-swizzled
    __shared__ alignas(16) __bf16 Ps[4][32*64];     // per-wave P^T [q=32][kv=64], chunk-swizzled

    const size_t kbase = (size_t)b*SEQ*QKW + 1024 + h*64;
    const size_t vbase = (size_t)bh*64*SEQ;
    const int sw = lm & 7;                          // row-swizzle key for frag reads (row&7==lm&7)

    auto issue = [&](int st, int buf) {
#pragma unroll
        for (int i = 0; i < 2; ++i) {
            int c = wv*128 + i*64 + ln;             // LDS chunk slot 0..511
            int row = c >> 3, p = c & 7;
            int cc = (p ^ (row & 7)) * 8;           // fetch the chunk that belongs at slot p
            gload_lds16(qk + kbase + (size_t)(st*64 + row)*QKW + cc, &Ks[buf][(wv*128 + i*64)*8]);
            gload_lds16(vT + vbase + (size_t)row*SEQ + st*64 + cc,   &Vs[buf][(wv*128 + i*64)*8]);
        }
    };

    // Q fragments (B-operand: B[n=lm][k=quad*8+j]) x 2 m-tiles, pre-scaled by 1/8 (exact pow2)
    bf16x8 qf[2][2];
#pragma unroll
    for (int mq = 0; mq < 2; ++mq)
#pragma unroll
        for (int kf = 0; kf < 2; ++kf) {
            bf16x8 t = *(const bf16x8*)&qk[(size_t)(b*SEQ + q0w + mq*16 + lm)*QKW + h*64 + kf*32 + quad*8];
#pragma unroll
            for (int j = 0; j < 8; ++j) t[j] = (__bf16)((float)t[j] * 0.125f);
            qf[mq][kf] = t;
        }

    f32x4 o[2][4] = {};                             // O^T: (dv = nb*16+quad*4+r, q = mq*16+lm)
    float lrow[2] = {0.f, 0.f};                     // per-lane P sums (reduced at end)
    const int nsteps = 2*qt + 2;

    issue(0, 0);                                    // prologue prefetch
    for (int st = 0; st < nsteps; ++st) {
        const int cur = st & 1;
        const int kv0 = st * 64;
        __syncthreads();                            // drains buf[cur] loads; frees buf[cur^1]
        if (st + 1 < nsteps) issue(st + 1, cur ^ 1);// prefetch flies during this step's compute

        // ---- S^T = K Q^T : kfrag shared across both m-tiles (the LDS economy)
        bf16x8 kfrag[4][2];
#pragma unroll
        for (int nt = 0; nt < 4; ++nt)
#pragma unroll
            for (int kf = 0; kf < 2; ++kf)
                kfrag[nt][kf] = *(const bf16x8*)&Ks[cur][(nt*16 + lm)*64 + ((kf*4 + quad) ^ sw)*8];
        f32x4 s[2][4] = {};
#pragma unroll
        for (int mq = 0; mq < 2; ++mq)
#pragma unroll
            for (int nt = 0; nt < 4; ++nt)
#pragma unroll
                for (int kf = 0; kf < 2; ++kf)
                    s[mq][nt] = __builtin_amdgcn_mfma_f32_16x16x32_bf16(kfrag[nt][kf], qf[mq][kf], s[mq][nt], 0, 0, 0);

        // ---- causal mask (diagonal steps only; exp(-1e9)=0 handles masked lanes)
        if (kv0 + 63 > q0w) {
#pragma unroll
            for (int mq = 0; mq < 2; ++mq) {
                int qg = q0w + mq*16 + lm;
#pragma unroll
                for (int nt = 0; nt < 4; ++nt)
#pragma unroll
                    for (int r = 0; r < 4; ++r) {
                        int kvg = kv0 + nt*16 + quad*4 + r;
                        if (kvg > qg) s[mq][nt][r] = -1e9f;
                    }
            }
        }

        // ---- no-max softmax: P = exp(s), per-lane running sums, no rescale
#pragma unroll
        for (int mq = 0; mq < 2; ++mq)
#pragma unroll
            for (int nt = 0; nt < 4; ++nt) {
                bf16x4 pb;
#pragma unroll
                for (int r = 0; r < 4; ++r) {
                    float p = __expf(s[mq][nt][r]);
                    __bf16 x = (__bf16)p;
                    pb[r] = x;
                    lrow[mq] += (float)x;           // sum the values PV actually uses
                }
                int pos = ((nt*2 + (quad >> 1)) ^ sw);
                *(bf16x4*)&Ps[wv][(mq*16 + lm)*64 + pos*8 + (quad & 1)*4] = pb;
            }

        // ---- O^T += V^T P^T  (vfrag shared across both m-tiles; wave-local LDS RAW)
        bf16x8 vfrag[4][2];
#pragma unroll
        for (int nb = 0; nb < 4; ++nb)
#pragma unroll
            for (int kf = 0; kf < 2; ++kf)
                vfrag[nb][kf] = *(const bf16x8*)&Vs[cur][(nb*16 + lm)*64 + ((kf*4 + quad) ^ sw)*8];
#pragma unroll
        for (int mq = 0; mq < 2; ++mq) {
            bf16x8 pf0 = *(const bf16x8*)&Ps[wv][(mq*16 + lm)*64 + ((0*4 + quad) ^ sw)*8];
            bf16x8 pf1 = *(const bf16x8*)&Ps[wv][(mq*16 + lm)*64 + ((1*4 + quad) ^ sw)*8];
#pragma unroll
            for (int nb = 0; nb < 4; ++nb) {
                o[mq][nb] = __builtin_amdgcn_mfma_f32_16x16x32_bf16(vfrag[nb][0], pf0, o[mq][nb], 0, 0, 0);
                o[mq][nb] = __builtin_amdgcn_mfma_f32_16x16x32_bf16(vfrag[nb][1], pf1, o[mq][nb], 0, 0, 0);
            }
        }
    }

    // ---- final l reduction (once): lanes with same lm share q
#pragma unroll
    for (int mq = 0; mq < 2; ++mq) {
        lrow[mq] += __shfl_xor(lrow[mq], 16);
        lrow[mq] += __shfl_xor(lrow[mq], 32);
    }

    // ---- epilogue: out[b][q][h*64+dv] = O^T(dv,q)/l ; 4 contiguous dv per lane -> float4
#pragma unroll
    for (int mq = 0; mq < 2; ++mq) {
        const float invl = 1.0f / lrow[mq];
        float* orow = out + (size_t)(b*SEQ + q0w + mq*16 + lm)*DIM + h*64;
#pragma unroll
        for (int nb = 0; nb < 4; ++nb) {
            float4 vres;
            vres.x = o[mq][nb][0] * invl;
            vres.y = o[mq][nb][1] * invl;
            vres.z = o[mq][nb][2] * invl;
            vres.w = o[mq][nb][3] * invl;
            *(float4*)&orow[nb*16 + quad*4] = vres;
        }
    }
}

// ---------------------------------------------------------------- launcher
extern "C" void kernel_launch(void* const* d_in, const int* in_sizes, int n_in,
                              void* d_out, int out_size, void* d_ws, size_t ws_size,
                              hipStream_t stream) {
    const float* x   = (const float*)d_in[0];
    const float* Wqk = (const float*)d_in[1];
    const float* bqk = (const float*)d_in[2];
    const float* Wv  = (const float*)d_in[3];
    const float* bv  = (const float*)d_in[4];
    float* out = (float*)d_out;

    char* ws = (char*)d_ws;
    const size_t SZ_XB = (size_t)MROWS*KDIM*2;    // 8 MB
    const size_t SZ_WT = (size_t)NTOT*KDIM*2;     // 6 MB
    const size_t SZ_QK = (size_t)MROWS*QKW*2;     // 16 MB
    __bf16* xb = (__bf16*)(ws);
    __bf16* Wt = (__bf16*)(ws + SZ_XB);
    __bf16* qk = (__bf16*)(ws + SZ_XB + SZ_WT);
    __bf16* vT = (__bf16*)(ws + SZ_XB + SZ_WT + SZ_QK);   // 8 MB

    prep_kernel    <<<4096 + 768, 256, 0, stream>>>(x, Wqk, Wv, xb, Wt);
    gemm_qkv_kernel<<<dim3(NTOT/BN, MROWS/BM), 256, 0, stream>>>(xb, Wt, bqk, bv, qk, vT);
    attn_kernel    <<<dim3(32, 16), 256, 0, stream>>>(qk, vT, out);
}

// Round 8
// 163.899 us; speedup vs baseline: 1.0548x; 1.0548x over previous
//
#include <hip/hip_runtime.h>
#include <hip/hip_bf16.h>
#include <math.h>

// Problem constants
#define BATCH 2
#define SEQ   2048
#define DIM   1024
#define HEADS 16
#define DH    64
#define MROWS (BATCH*SEQ)      // 4096
#define NTOT  3072             // gemm output cols: q(1024) | k(1024) | v(1024)
#define QKW   2048             // qk buffer width (v goes straight to vT)
#define KDIM  1024

typedef float f32x4 __attribute__((ext_vector_type(4)));
typedef __bf16 bf16x8 __attribute__((ext_vector_type(8)));
typedef __bf16 bf16x4 __attribute__((ext_vector_type(4)));

__device__ __forceinline__ void gload_lds16(const void* g, void* l) {
    // async global->LDS, 16B per lane; LDS dest must be wave-uniform base (+lane*16 implicit)
    __builtin_amdgcn_global_load_lds((__attribute__((address_space(1))) void*)g,
                                     (__attribute__((address_space(3))) void*)l,
                                     16, 0, 0);
}

// ---------------------------------------------- prep: cast x -> bf16  +  transpose W -> Wt
// blocks [0,4096): cast 1 float4/thread.  blocks [4096,4864): 64x64 transpose tiles.
__global__ void prep_kernel(const float* __restrict__ x,
                            const float* __restrict__ Wqk, const float* __restrict__ Wv,
                            __bf16* __restrict__ xb, __bf16* __restrict__ Wt) {
    __shared__ float T[64*65];
    const int bx = blockIdx.x;
    const int tid = threadIdx.x;
    if (bx < 4096) {
        int i = bx * 256 + tid;                   // 1M float4 = 4M floats exactly
        float4 f = ((const float4*)x)[i];
        bf16x4 o;
        o.x = (__bf16)f.x; o.y = (__bf16)f.y; o.z = (__bf16)f.z; o.w = (__bf16)f.w;
        ((bf16x4*)xb)[i] = o;
    } else {
        const int t = bx - 4096;                  // 0..767
        const int n0 = (t % 48) * 64;
        const int k0 = (t / 48) * 64;
#pragma unroll
        for (int i = 0; i < 16; ++i) {
            int idx = i*256 + tid;
            int kk = idx >> 6, nn = idx & 63;
            int n = n0 + nn;
            float v = (n < 2048) ? Wqk[(size_t)(k0+kk)*2048 + n]
                                 : Wv [(size_t)(k0+kk)*1024 + (n - 2048)];
            T[kk*65 + nn] = v;
        }
        __syncthreads();
#pragma unroll
        for (int i = 0; i < 16; ++i) {
            int idx = i*256 + tid;
            int nn = idx >> 6, kk = idx & 63;
            Wt[(size_t)(n0+nn)*KDIM + k0 + kk] = (__bf16)T[kk*65 + nn];
        }
    }
}

// ---------------------------------------------------------------- GEMM v3: BK=64 + LDS dbuf
// [qk | v] = x * Wt^T + bias ; qk cols<2048 -> qk buffer row-major (stride QKW),
// v cols>=2048 -> written TRANSPOSED to vT[bh][dv][s].
// Double-buffered staging: ONE barrier/iter; prefetch kt+1 issued right after the barrier,
// so the next barrier's vmcnt(0) drain covers loads that had a full compute phase in flight.
// (Co-resident blocks run barrier-lockstep and can't hide the drain for each other - R7 PM.)
// XOR chunk swizzle (p ^ (row&7)) -> conflict-free b128 frag reads. K order unchanged vs r6.
#define BM 128
#define BN 128
#define BK 64

__global__ __launch_bounds__(256) void gemm_qkv_kernel(const __bf16* __restrict__ A,
                                                       const __bf16* __restrict__ Bt,
                                                       const float* __restrict__ bqk,
                                                       const float* __restrict__ bv,
                                                       __bf16* __restrict__ qk,
                                                       __bf16* __restrict__ vT) {
    __shared__ alignas(16) __bf16 As[2][BM*BK];   // 2 x 16 KB
    __shared__ alignas(16) __bf16 Bs[2][BN*BK];   // 2 x 16 KB  (64 KB total -> 2 blocks/CU)
    const int tid = threadIdx.x;
    const int wv = tid >> 6, ln = tid & 63;
    const int quad = ln >> 4, lm = ln & 15;
    const int m0 = blockIdx.y * BM, n0 = blockIdx.x * BN;
    const int wm = (wv >> 1) * 64, wn = (wv & 1) * 64;
    const int sw = lm & 7;                         // frag-read swizzle key (row&7 == lm&7)

    auto issue = [&](int kt, int buf) {
#pragma unroll
        for (int i = 0; i < 4; ++i) {
            int slot = wv*256 + i*64 + ln;        // LDS chunk slot 0..1023 (16B chunks)
            int row = slot >> 3, p = slot & 7;
            int cc = (p ^ (row & 7)) * 8;         // fetch the chunk that belongs at slot p
            gload_lds16(A  + (size_t)(m0 + row)*KDIM + kt*BK + cc, &As[buf][(wv*256 + i*64)*8]);
            gload_lds16(Bt + (size_t)(n0 + row)*KDIM + kt*BK + cc, &Bs[buf][(wv*256 + i*64)*8]);
        }
    };

    f32x4 acc[4][4] = {};

    issue(0, 0);                                  // prologue prefetch
    for (int kt = 0; kt < KDIM/BK; ++kt) {
        const int cur = kt & 1;
        __syncthreads();          // drains buf[cur] loads; all waves past buf[cur^1] reads
        if (kt + 1 < KDIM/BK) issue(kt + 1, cur ^ 1);   // flies during this iter's compute
#pragma unroll
        for (int kf = 0; kf < 2; ++kf) {          // two 32-wide K halves per staged tile
            bf16x8 af[4], bfr[4];
#pragma unroll
            for (int mt = 0; mt < 4; ++mt)
                af[mt] = *(const bf16x8*)&As[cur][(wm + mt*16 + lm)*BK + (((kf<<2)|quad) ^ sw)*8];
#pragma unroll
            for (int nt = 0; nt < 4; ++nt)
                bfr[nt] = *(const bf16x8*)&Bs[cur][(wn + nt*16 + lm)*BK + (((kf<<2)|quad) ^ sw)*8];
#pragma unroll
            for (int mt = 0; mt < 4; ++mt)
#pragma unroll
                for (int nt = 0; nt < 4; ++nt)
                    acc[mt][nt] = __builtin_amdgcn_mfma_f32_16x16x32_bf16(af[mt], bfr[nt], acc[mt][nt], 0, 0, 0);
        }
    }
    // epilogue. C/D layout: row = quad*4+r, col = lm (m89-verified). Branch is block-uniform.
    if (n0 < 2048) {
#pragma unroll
        for (int mt = 0; mt < 4; ++mt) {
            int rbase = m0 + wm + mt*16 + quad*4;
#pragma unroll
            for (int nt = 0; nt < 4; ++nt) {
                int col = n0 + wn + nt*16 + lm;
                float bs = bqk[col];
#pragma unroll
                for (int r = 0; r < 4; ++r)
                    qk[(size_t)(rbase + r)*QKW + col] = (__bf16)(acc[mt][nt][r] + bs);
            }
        }
    } else {
        // v path: vT[((b*16+h)*64 + dv)*SEQ + s]; r-values are s-contiguous -> 8B stores
#pragma unroll
        for (int mt = 0; mt < 4; ++mt) {
            int rbase = m0 + wm + mt*16 + quad*4;       // global token index, mult of 4
            int bb = rbase >> 11, s = rbase & 2047;     // rbase..rbase+3 same batch
#pragma unroll
            for (int nt = 0; nt < 4; ++nt) {
                int cv = n0 + wn + nt*16 + lm - 2048;   // v column 0..1023
                int hh = cv >> 6, dv = cv & 63;
                float bs = bv[cv];
                bf16x4 pk;
#pragma unroll
                for (int r = 0; r < 4; ++r) pk[r] = (__bf16)(acc[mt][nt][r] + bs);
                *(bf16x4*)&vT[(((size_t)(bb*16 + hh))*64 + dv)*SEQ + s] = pk;
            }
        }
    }
}

// ---------------------------------------------------------------- flash attention v5 (r6 revert)
// Transposed-S (S^T = K Q^T, O^T = V^T P^T) + dbuf prefetch + XOR-swizzled LDS + no-max softmax.
// grid (32 bh, 32 qtiles heavy-first), 256 thr = 4 waves; 16 q-rows/wave; KV tile 64.
// LDS 40 KB -> 4 blocks/CU (__launch_bounds__(256,4)).

__global__ __launch_bounds__(256, 4) void attn_kernel(const __bf16* __restrict__ qk,
                                                      const __bf16* __restrict__ vT,
                                                      float* __restrict__ out) {
    const int bh = blockIdx.x;
    const int b = bh >> 4, h = bh & 15;
    const int qt = 31 - (int)blockIdx.y;            // heavy blocks dispatched first
    const int qb = qt * 64;
    const int tid = threadIdx.x, wv = tid >> 6, ln = tid & 63;
    const int quad = ln >> 4, lm = ln & 15;
    const int q0w = qb + wv*16;                     // this wave's 16 q-rows
    const int qg = q0w + lm;                        // this lane's q row

    __shared__ alignas(16) __bf16 Ks[2][64*64];     // [buf][kv][feat], chunk-swizzled
    __shared__ alignas(16) __bf16 Vs[2][64*64];     // [buf][dv][kv],  chunk-swizzled
    __shared__ alignas(16) __bf16 Ps[4][16*64];     // per-wave P^T [q][kv], chunk-swizzled

    const size_t kbase = (size_t)b*SEQ*QKW + 1024 + h*64;
    const size_t vbase = (size_t)bh*64*SEQ;
    const int sw = lm & 7;                          // row-swizzle key for frag reads (row&7==lm&7)

    auto issue = [&](int st, int buf) {
#pragma unroll
        for (int i = 0; i < 2; ++i) {
            int c = wv*128 + i*64 + ln;             // LDS chunk slot 0..511
            int row = c >> 3, p = c & 7;
            int cc = (p ^ (row & 7)) * 8;           // fetch the chunk that belongs at slot p
            gload_lds16(qk + kbase + (size_t)(st*64 + row)*QKW + cc, &Ks[buf][(wv*128 + i*64)*8]);
            gload_lds16(vT + vbase + (size_t)row*SEQ + st*64 + cc,   &Vs[buf][(wv*128 + i*64)*8]);
        }
    };

    // Q fragments (B-operand: B[n=lm][k=quad*8+j]), pre-scaled by 1/8 (exact pow2)
    bf16x8 qf[2];
#pragma unroll
    for (int kf = 0; kf < 2; ++kf) {
        bf16x8 t = *(const bf16x8*)&qk[(size_t)(b*SEQ + q0w + lm)*QKW + h*64 + kf*32 + quad*8];
#pragma unroll
        for (int j = 0; j < 8; ++j) t[j] = (__bf16)((float)t[j] * 0.125f);
        qf[kf] = t;
    }

    f32x4 o[4] = {};                                // O^T: (dv = nb*16+quad*4+r, q = lm)
    float lrow = 0.f;                               // per-lane partial sum of P (reduced at end)
    const int nsteps = qt + 1;

    issue(0, 0);                                    // prologue prefetch
    for (int st = 0; st < nsteps; ++st) {
        const int cur = st & 1;
        const int kv0 = st * 64;
        __syncthreads();                            // drains buf[cur] loads; frees buf[cur^1]
        if (st + 1 < nsteps) issue(st + 1, cur ^ 1);// prefetch flies during this step's compute

        // ---- S^T = K Q^T : tile nt holds kv rows [nt*16, nt*16+16)
        f32x4 s[4] = {};
        bf16x8 kfrag[4][2];
#pragma unroll
        for (int nt = 0; nt < 4; ++nt)
#pragma unroll
            for (int kf = 0; kf < 2; ++kf)
                kfrag[nt][kf] = *(const bf16x8*)&Ks[cur][(nt*16 + lm)*64 + ((kf*4 + quad) ^ sw)*8];
#pragma unroll
        for (int nt = 0; nt < 4; ++nt)
#pragma unroll
            for (int kf = 0; kf < 2; ++kf)
                s[nt] = __builtin_amdgcn_mfma_f32_16x16x32_bf16(kfrag[nt][kf], qf[kf], s[nt], 0, 0, 0);

        // ---- causal mask (only the diagonal step; exp(-1e9)=0 handles masked lanes)
        if (kv0 + 63 > q0w) {
#pragma unroll
            for (int nt = 0; nt < 4; ++nt)
#pragma unroll
                for (int r = 0; r < 4; ++r) {
                    int kvg = kv0 + nt*16 + quad*4 + r;
                    if (kvg > qg) s[nt][r] = -1e9f;
                }
        }

        // ---- no-max softmax: P = exp(s), per-lane running sum, no rescale
#pragma unroll
        for (int nt = 0; nt < 4; ++nt) {
            bf16x4 pb;
#pragma unroll
            for (int r = 0; r < 4; ++r) {
                float p = __expf(s[nt][r]);
                __bf16 x = (__bf16)p;
                pb[r] = x;
                lrow += (float)x;                   // sum the values PV actually uses
            }
            // P chunk-swizzled store: 8B unit u = nt*4+quad -> chunk j = u>>1, half = u&1
            int pos = ((nt*2 + (quad >> 1)) ^ sw);
            *(bf16x4*)&Ps[wv][lm*64 + pos*8 + (quad & 1)*4] = pb;
        }

        // ---- O^T += V^T P^T  (A = V^T frag, B = P^T frag; wave-local LDS RAW)
        bf16x8 vfrag[4][2];
#pragma unroll
        for (int nb = 0; nb < 4; ++nb)
#pragma unroll
            for (int kf = 0; kf < 2; ++kf)
                vfrag[nb][kf] = *(const bf16x8*)&Vs[cur][(nb*16 + lm)*64 + ((kf*4 + quad) ^ sw)*8];
        bf16x8 pf0 = *(const bf16x8*)&Ps[wv][lm*64 + ((0*4 + quad) ^ sw)*8];
        bf16x8 pf1 = *(const bf16x8*)&Ps[wv][lm*64 + ((1*4 + quad) ^ sw)*8];
#pragma unroll
        for (int nb = 0; nb < 4; ++nb) {
            o[nb] = __builtin_amdgcn_mfma_f32_16x16x32_bf16(vfrag[nb][0], pf0, o[nb], 0, 0, 0);
            o[nb] = __builtin_amdgcn_mfma_f32_16x16x32_bf16(vfrag[nb][1], pf1, o[nb], 0, 0, 0);
        }
    }

    // ---- final l reduction (once, not per step): lanes with same lm share q
    lrow += __shfl_xor(lrow, 16);
    lrow += __shfl_xor(lrow, 32);

    // ---- epilogue: out[b][q][h*64+dv] = O^T(dv,q)/l ; 4 contiguous dv per lane -> float4
    const float invl = 1.0f / lrow;
    float* orow = out + (size_t)(b*SEQ + q0w + lm)*DIM + h*64;
#pragma unroll
    for (int nb = 0; nb < 4; ++nb) {
        float4 vres;
        vres.x = o[nb][0] * invl;
        vres.y = o[nb][1] * invl;
        vres.z = o[nb][2] * invl;
        vres.w = o[nb][3] * invl;
        *(float4*)&orow[nb*16 + quad*4] = vres;
    }
}

// ---------------------------------------------------------------- launcher
extern "C" void kernel_launch(void* const* d_in, const int* in_sizes, int n_in,
                              void* d_out, int out_size, void* d_ws, size_t ws_size,
                              hipStream_t stream) {
    const float* x   = (const float*)d_in[0];
    const float* Wqk = (const float*)d_in[1];
    const float* bqk = (const float*)d_in[2];
    const float* Wv  = (const float*)d_in[3];
    const float* bv  = (const float*)d_in[4];
    float* out = (float*)d_out;

    char* ws = (char*)d_ws;
    const size_t SZ_XB = (size_t)MROWS*KDIM*2;    // 8 MB
    const size_t SZ_WT = (size_t)NTOT*KDIM*2;     // 6 MB
    const size_t SZ_QK = (size_t)MROWS*QKW*2;     // 16 MB
    __bf16* xb = (__bf16*)(ws);
    __bf16* Wt = (__bf16*)(ws + SZ_XB);
    __bf16* qk = (__bf16*)(ws + SZ_XB + SZ_WT);
    __bf16* vT = (__bf16*)(ws + SZ_XB + SZ_WT + SZ_QK);   // 8 MB

    prep_kernel    <<<4096 + 768, 256, 0, stream>>>(x, Wqk, Wv, xb, Wt);
    gemm_qkv_kernel<<<dim3(NTOT/BN, MROWS/BM), 256, 0, stream>>>(xb, Wt, bqk, bv, qk, vT);
    attn_kernel    <<<dim3(32, 32), 256, 0, stream>>>(qk, vT, out);
}

// Round 9
// 156.695 us; speedup vs baseline: 1.1033x; 1.0460x over previous
//
#include <hip/hip_runtime.h>
#include <hip/hip_bf16.h>
#include <math.h>

// Problem constants
#define BATCH 2
#define SEQ   2048
#define DIM   1024
#define HEADS 16
#define DH    64
#define MROWS (BATCH*SEQ)      // 4096
#define NTOT  3072             // gemm output cols: q(1024) | k(1024) | v(1024)
#define QKW   2048             // qk buffer width (v goes straight to vT)
#define KDIM  1024

typedef float f32x4 __attribute__((ext_vector_type(4)));
typedef __bf16 bf16x8 __attribute__((ext_vector_type(8)));
typedef __bf16 bf16x4 __attribute__((ext_vector_type(4)));

__device__ __forceinline__ void gload_lds16(const void* g, void* l) {
    // async global->LDS, 16B per lane; LDS dest must be wave-uniform base (+lane*16 implicit)
    __builtin_amdgcn_global_load_lds((__attribute__((address_space(1))) void*)g,
                                     (__attribute__((address_space(3))) void*)l,
                                     16, 0, 0);
}

// ---------------------------------------------- prep: cast x -> bf16  +  transpose W -> Wt
// blocks [0,4096): cast 1 float4/thread.  blocks [4096,4864): 64x64 transpose tiles.
__global__ void prep_kernel(const float* __restrict__ x,
                            const float* __restrict__ Wqk, const float* __restrict__ Wv,
                            __bf16* __restrict__ xb, __bf16* __restrict__ Wt) {
    __shared__ float T[64*65];
    const int bx = blockIdx.x;
    const int tid = threadIdx.x;
    if (bx < 4096) {
        int i = bx * 256 + tid;                   // 1M float4 = 4M floats exactly
        float4 f = ((const float4*)x)[i];
        bf16x4 o;
        o.x = (__bf16)f.x; o.y = (__bf16)f.y; o.z = (__bf16)f.z; o.w = (__bf16)f.w;
        ((bf16x4*)xb)[i] = o;
    } else {
        const int t = bx - 4096;                  // 0..767
        const int n0 = (t % 48) * 64;
        const int k0 = (t / 48) * 64;
#pragma unroll
        for (int i = 0; i < 16; ++i) {
            int idx = i*256 + tid;
            int kk = idx >> 6, nn = idx & 63;
            int n = n0 + nn;
            float v = (n < 2048) ? Wqk[(size_t)(k0+kk)*2048 + n]
                                 : Wv [(size_t)(k0+kk)*1024 + (n - 2048)];
            T[kk*65 + nn] = v;
        }
        __syncthreads();
#pragma unroll
        for (int i = 0; i < 16; ++i) {
            int idx = i*256 + tid;
            int nn = idx >> 6, kk = idx & 63;
            Wt[(size_t)(n0+nn)*KDIM + k0 + kk] = (__bf16)T[kk*65 + nn];
        }
    }
}

// ---------------------------------------------------------------- GEMM v4: BK=64 + swizzle
// [qk | v] = x * Wt^T + bias.
// qk blocks (n0<2048): compute C^T via mfma(B,A) -> lane holds 4 consecutive n -> 8B stores
//   (16 store insts/wave vs 64 scalar). Bit-identical sums (same dot products).
// v  blocks: normal orientation, transposed 8B stores to vT[bh][dv][s].
#define BM 128
#define BN 128
#define BK 64

__global__ __launch_bounds__(256) void gemm_qkv_kernel(const __bf16* __restrict__ A,
                                                       const __bf16* __restrict__ Bt,
                                                       const float* __restrict__ bqk,
                                                       const float* __restrict__ bv,
                                                       __bf16* __restrict__ qk,
                                                       __bf16* __restrict__ vT) {
    __shared__ alignas(16) __bf16 As[BM*BK];      // [row][chunk-swizzled 8x16B]
    __shared__ alignas(16) __bf16 Bs[BN*BK];
    const int tid = threadIdx.x;
    const int wv = tid >> 6, ln = tid & 63;
    const int quad = ln >> 4, lm = ln & 15;
    const int m0 = blockIdx.y * BM, n0 = blockIdx.x * BN;
    const int wm = (wv >> 1) * 64, wn = (wv & 1) * 64;
    const int sw = lm & 7;                         // frag-read swizzle key (row&7 == lm&7)

    f32x4 acc[4][4] = {};

    if (n0 < 2048) {
        // ---------------- qk path: acc[nt][mt] = C^T tiles ----------------
        for (int kt = 0; kt < KDIM/BK; ++kt) {
            const int k0 = kt * BK;
            __syncthreads();
#pragma unroll
            for (int i = 0; i < 4; ++i) {
                int slot = wv*256 + i*64 + ln;
                int row = slot >> 3, p = slot & 7;
                int cc = (p ^ (row & 7)) * 8;
                gload_lds16(A  + (size_t)(m0 + row)*KDIM + k0 + cc, &As[(wv*256 + i*64)*8]);
                gload_lds16(Bt + (size_t)(n0 + row)*KDIM + k0 + cc, &Bs[(wv*256 + i*64)*8]);
            }
            __syncthreads();
#pragma unroll
            for (int kf = 0; kf < 2; ++kf) {
                bf16x8 af[4], bfr[4];
#pragma unroll
                for (int mt = 0; mt < 4; ++mt)
                    af[mt] = *(const bf16x8*)&As[(wm + mt*16 + lm)*BK + (((kf<<2)|quad) ^ sw)*8];
#pragma unroll
                for (int nt = 0; nt < 4; ++nt)
                    bfr[nt] = *(const bf16x8*)&Bs[(wn + nt*16 + lm)*BK + (((kf<<2)|quad) ^ sw)*8];
#pragma unroll
                for (int nt = 0; nt < 4; ++nt)
#pragma unroll
                    for (int mt = 0; mt < 4; ++mt)
                        acc[nt][mt] = __builtin_amdgcn_mfma_f32_16x16x32_bf16(bfr[nt], af[mt], acc[nt][mt], 0, 0, 0);
            }
        }
        // epilogue: C^T layout -> lane(quad,lm): n = nt*16+quad*4+r (consecutive r), m = mt*16+lm
#pragma unroll
        for (int nt = 0; nt < 4; ++nt) {
            int nb = n0 + wn + nt*16 + quad*4;
            float4 bs4 = *(const float4*)&bqk[nb];
#pragma unroll
            for (int mt = 0; mt < 4; ++mt) {
                int m = m0 + wm + mt*16 + lm;
                bf16x4 pk;
                pk[0] = (__bf16)(acc[nt][mt][0] + bs4.x);
                pk[1] = (__bf16)(acc[nt][mt][1] + bs4.y);
                pk[2] = (__bf16)(acc[nt][mt][2] + bs4.z);
                pk[3] = (__bf16)(acc[nt][mt][3] + bs4.w);
                *(bf16x4*)&qk[(size_t)m*QKW + nb] = pk;
            }
        }
    } else {
        // ---------------- v path: acc[mt][nt] = C tiles, store transposed to vT ----------------
        for (int kt = 0; kt < KDIM/BK; ++kt) {
            const int k0 = kt * BK;
            __syncthreads();
#pragma unroll
            for (int i = 0; i < 4; ++i) {
                int slot = wv*256 + i*64 + ln;
                int row = slot >> 3, p = slot & 7;
                int cc = (p ^ (row & 7)) * 8;
                gload_lds16(A  + (size_t)(m0 + row)*KDIM + k0 + cc, &As[(wv*256 + i*64)*8]);
                gload_lds16(Bt + (size_t)(n0 + row)*KDIM + k0 + cc, &Bs[(wv*256 + i*64)*8]);
            }
            __syncthreads();
#pragma unroll
            for (int kf = 0; kf < 2; ++kf) {
                bf16x8 af[4], bfr[4];
#pragma unroll
                for (int mt = 0; mt < 4; ++mt)
                    af[mt] = *(const bf16x8*)&As[(wm + mt*16 + lm)*BK + (((kf<<2)|quad) ^ sw)*8];
#pragma unroll
                for (int nt = 0; nt < 4; ++nt)
                    bfr[nt] = *(const bf16x8*)&Bs[(wn + nt*16 + lm)*BK + (((kf<<2)|quad) ^ sw)*8];
#pragma unroll
                for (int mt = 0; mt < 4; ++mt)
#pragma unroll
                    for (int nt = 0; nt < 4; ++nt)
                        acc[mt][nt] = __builtin_amdgcn_mfma_f32_16x16x32_bf16(af[mt], bfr[nt], acc[mt][nt], 0, 0, 0);
            }
        }
        // vT[((b*16+h)*64 + dv)*SEQ + s]; r-values are s-contiguous -> 8B stores
#pragma unroll
        for (int mt = 0; mt < 4; ++mt) {
            int rbase = m0 + wm + mt*16 + quad*4;       // global token index, mult of 4
            int bb = rbase >> 11, s = rbase & 2047;     // rbase..rbase+3 same batch
#pragma unroll
            for (int nt = 0; nt < 4; ++nt) {
                int cv = n0 + wn + nt*16 + lm - 2048;   // v column 0..1023
                int hh = cv >> 6, dv = cv & 63;
                float bs = bv[cv];
                bf16x4 pk;
#pragma unroll
                for (int r = 0; r < 4; ++r) pk[r] = (__bf16)(acc[mt][nt][r] + bs);
                *(bf16x4*)&vT[(((size_t)(bb*16 + hh))*64 + dv)*SEQ + s] = pk;
            }
        }
    }
}

// ---------------------------------------------------------------- flash attention v7
// Transposed-S + XOR swizzle + no-max softmax + K/V dbuf prefetch (r6 base), plus:
//   - Q pre-scaled by 0.125*log2(e) -> P = exp2(s): kills 16 v_mul/wave-step
//   - l accumulated by ones-MFMA (D[i][j] = sum_k P^T[j][k], identical rows): kills the
//     16 v_add/wave-step AND the final shfl reduction (every lane holds l(q=lm)).
// grid (32 bh, 32 qtiles heavy-first), 256 thr = 4 waves; 16 q-rows/wave; KV tile 64.
// LDS 40 KB -> 4 blocks/CU (__launch_bounds__(256,4)).

__global__ __launch_bounds__(256, 4) void attn_kernel(const __bf16* __restrict__ qk,
                                                      const __bf16* __restrict__ vT,
                                                      float* __restrict__ out) {
    const int bh = blockIdx.x;
    const int b = bh >> 4, h = bh & 15;
    const int qt = 31 - (int)blockIdx.y;            // heavy blocks dispatched first
    const int qb = qt * 64;
    const int tid = threadIdx.x, wv = tid >> 6, ln = tid & 63;
    const int quad = ln >> 4, lm = ln & 15;
    const int q0w = qb + wv*16;                     // this wave's 16 q-rows
    const int qg = q0w + lm;                        // this lane's q row

    __shared__ alignas(16) __bf16 Ks[2][64*64];     // [buf][kv][feat], chunk-swizzled
    __shared__ alignas(16) __bf16 Vs[2][64*64];     // [buf][dv][kv],  chunk-swizzled
    __shared__ alignas(16) __bf16 Ps[4][16*64];     // per-wave P^T [q][kv], chunk-swizzled

    const size_t kbase = (size_t)b*SEQ*QKW + 1024 + h*64;
    const size_t vbase = (size_t)bh*64*SEQ;
    const int sw = lm & 7;                          // row-swizzle key for frag reads (row&7==lm&7)

    auto issue = [&](int st, int buf) {
#pragma unroll
        for (int i = 0; i < 2; ++i) {
            int c = wv*128 + i*64 + ln;             // LDS chunk slot 0..511
            int row = c >> 3, p = c & 7;
            int cc = (p ^ (row & 7)) * 8;           // fetch the chunk that belongs at slot p
            gload_lds16(qk + kbase + (size_t)(st*64 + row)*QKW + cc, &Ks[buf][(wv*128 + i*64)*8]);
            gload_lds16(vT + vbase + (size_t)row*SEQ + st*64 + cc,   &Vs[buf][(wv*128 + i*64)*8]);
        }
    };

    // Q fragments (B-operand), pre-scaled by 0.125*log2(e) so P = exp2(S)
    const float qscale = 0.125f * 1.44269504088896f;
    bf16x8 qf[2];
#pragma unroll
    for (int kf = 0; kf < 2; ++kf) {
        bf16x8 t = *(const bf16x8*)&qk[(size_t)(b*SEQ + q0w + lm)*QKW + h*64 + kf*32 + quad*8];
#pragma unroll
        for (int j = 0; j < 8; ++j) t[j] = (__bf16)((float)t[j] * qscale);
        qf[kf] = t;
    }
    bf16x8 ones;
#pragma unroll
    for (int j = 0; j < 8; ++j) ones[j] = (__bf16)1.0f;

    f32x4 o[4] = {};                                // O^T: (dv = nb*16+quad*4+r, q = lm)
    f32x4 o5 = {};                                  // l accumulator: every reg = l(q=lm)
    const int nsteps = qt + 1;

    issue(0, 0);                                    // prologue prefetch
    for (int st = 0; st < nsteps; ++st) {
        const int cur = st & 1;
        const int kv0 = st * 64;
        __syncthreads();                            // drains buf[cur] loads; frees buf[cur^1]
        if (st + 1 < nsteps) issue(st + 1, cur ^ 1);// prefetch flies during this step's compute

        // ---- S^T = K Q^T : tile nt holds kv rows [nt*16, nt*16+16)
        f32x4 s[4] = {};
        bf16x8 kfrag[4][2];
#pragma unroll
        for (int nt = 0; nt < 4; ++nt)
#pragma unroll
            for (int kf = 0; kf < 2; ++kf)
                kfrag[nt][kf] = *(const bf16x8*)&Ks[cur][(nt*16 + lm)*64 + ((kf*4 + quad) ^ sw)*8];
#pragma unroll
        for (int nt = 0; nt < 4; ++nt)
#pragma unroll
            for (int kf = 0; kf < 2; ++kf)
                s[nt] = __builtin_amdgcn_mfma_f32_16x16x32_bf16(kfrag[nt][kf], qf[kf], s[nt], 0, 0, 0);

        // ---- causal mask (only the diagonal step; exp2(-1e9)=0 handles masked lanes)
        if (kv0 + 63 > q0w) {
#pragma unroll
            for (int nt = 0; nt < 4; ++nt)
#pragma unroll
                for (int r = 0; r < 4; ++r) {
                    int kvg = kv0 + nt*16 + quad*4 + r;
                    if (kvg > qg) s[nt][r] = -1e9f;
                }
        }

        // ---- no-max softmax: P = exp2(s) (log2e folded into Q), store to per-wave LDS
#pragma unroll
        for (int nt = 0; nt < 4; ++nt) {
            bf16x4 pb;
#pragma unroll
            for (int r = 0; r < 4; ++r)
                pb[r] = (__bf16)exp2f(s[nt][r]);
            int pos = ((nt*2 + (quad >> 1)) ^ sw);
            *(bf16x4*)&Ps[wv][lm*64 + pos*8 + (quad & 1)*4] = pb;   // 8B vectorized store
        }

        // ---- O^T += V^T P^T ; l += 1^T P^T  (wave-local LDS RAW, no barrier)
        bf16x8 vfrag[4][2];
#pragma unroll
        for (int nb = 0; nb < 4; ++nb)
#pragma unroll
            for (int kf = 0; kf < 2; ++kf)
                vfrag[nb][kf] = *(const bf16x8*)&Vs[cur][(nb*16 + lm)*64 + ((kf*4 + quad) ^ sw)*8];
        bf16x8 pf0 = *(const bf16x8*)&Ps[wv][lm*64 + ((0*4 + quad) ^ sw)*8];
        bf16x8 pf1 = *(const bf16x8*)&Ps[wv][lm*64 + ((1*4 + quad) ^ sw)*8];
#pragma unroll
        for (int nb = 0; nb < 4; ++nb) {
            o[nb] = __builtin_amdgcn_mfma_f32_16x16x32_bf16(vfrag[nb][0], pf0, o[nb], 0, 0, 0);
            o[nb] = __builtin_amdgcn_mfma_f32_16x16x32_bf16(vfrag[nb][1], pf1, o[nb], 0, 0, 0);
        }
        o5 = __builtin_amdgcn_mfma_f32_16x16x32_bf16(ones, pf0, o5, 0, 0, 0);
        o5 = __builtin_amdgcn_mfma_f32_16x16x32_bf16(ones, pf1, o5, 0, 0, 0);
    }

    // ---- epilogue: every lane already holds l(q=lm) in o5 (all rows of 1^T P^T identical)
    const float invl = 1.0f / o5[0];
    float* orow = out + (size_t)(b*SEQ + q0w + lm)*DIM + h*64;
#pragma unroll
    for (int nb = 0; nb < 4; ++nb) {
        float4 vres;
        vres.x = o[nb][0] * invl;
        vres.y = o[nb][1] * invl;
        vres.z = o[nb][2] * invl;
        vres.w = o[nb][3] * invl;
        *(float4*)&orow[nb*16 + quad*4] = vres;
    }
}

// ---------------------------------------------------------------- launcher
extern "C" void kernel_launch(void* const* d_in, const int* in_sizes, int n_in,
                              void* d_out, int out_size, void* d_ws, size_t ws_size,
                              hipStream_t stream) {
    const float* x   = (const float*)d_in[0];
    const float* Wqk = (const float*)d_in[1];
    const float* bqk = (const float*)d_in[2];
    const float* Wv  = (const float*)d_in[3];
    const float* bv  = (const float*)d_in[4];
    float* out = (float*)d_out;

    char* ws = (char*)d_ws;
    const size_t SZ_XB = (size_t)MROWS*KDIM*2;    // 8 MB
    const size_t SZ_WT = (size_t)NTOT*KDIM*2;     // 6 MB
    const size_t SZ_QK = (size_t)MROWS*QKW*2;     // 16 MB
    __bf16* xb = (__bf16*)(ws);
    __bf16* Wt = (__bf16*)(ws + SZ_XB);
    __bf16* qk = (__bf16*)(ws + SZ_XB + SZ_WT);
    __bf16* vT = (__bf16*)(ws + SZ_XB + SZ_WT + SZ_QK);   // 8 MB

    prep_kernel    <<<4096 + 768, 256, 0, stream>>>(x, Wqk, Wv, xb, Wt);
    gemm_qkv_kernel<<<dim3(NTOT/BN, MROWS/BM), 256, 0, stream>>>(xb, Wt, bqk, bv, qk, vT);
    attn_kernel    <<<dim3(32, 32), 256, 0, stream>>>(qk, vT, out);
}